// Round 13
// baseline (1156.222 us; speedup 1.0000x reference)
//
#include <hip/hip_runtime.h>
#include <hip/hip_bf16.h>
#include <stdint.h>

#define BB 4
#define SS 4096
#define DD 256

typedef __attribute__((ext_vector_type(4))) float f32x4;
typedef __attribute__((ext_vector_type(8))) short s16x8;

__device__ __forceinline__ ushort f2bf(float f) {
  __hip_bfloat16 h = __float2bfloat16(f);
  return __builtin_bit_cast(ushort, h);
}

// pack 8 consecutive f32 -> 8 bf16 (RNE)
__device__ __forceinline__ s16x8 pack8(const float* __restrict__ p) {
  const float4 a = *(const float4*)p;
  const float4 b = *(const float4*)(p + 4);
  s16x8 r;
  r[0] = (short)f2bf(a.x); r[1] = (short)f2bf(a.y);
  r[2] = (short)f2bf(a.z); r[3] = (short)f2bf(a.w);
  r[4] = (short)f2bf(b.x); r[5] = (short)f2bf(b.y);
  r[6] = (short)f2bf(b.z); r[7] = (short)f2bf(b.w);
  return r;
}

// ---------------- kernel 1: fused convert + QKV projection GEMM ----------------
#define LROW 40  // 80B row stride: multiple of 16B (b128-safe), odd dw-quad (conflict-free)

__global__ __launch_bounds__(256) void proj_gemm(const float* __restrict__ X,
                                                 const float* __restrict__ Wq,
                                                 const float* __restrict__ Wk,
                                                 const float* __restrict__ Wv,
                                                 const float* __restrict__ bq,
                                                 const float* __restrict__ bk,
                                                 const float* __restrict__ bv,
                                                 ushort* __restrict__ Qb,
                                                 ushort* __restrict__ Kb,
                                                 ushort* __restrict__ Vt) {
  __shared__ ushort Al[128 * LROW];
  __shared__ ushort Bl[128 * LROW];
  const int m0 = blockIdx.x * 128;
  const int n0 = blockIdx.y * 128;
  const int region = n0 >> 8;          // 0=Q, 1=K, 2=V (blocks never straddle)
  const int n0l = n0 & 255;
  const float* Wsel = (region == 0) ? Wq : (region == 1) ? Wk : Wv;
  const float* bsel = (region == 0) ? bq : (region == 1) ? bk : bv;
  const int t = threadIdx.x;
  const int lane = t & 63;
  const int w = t >> 6;
  const int wr = w & 1, wc = w >> 1;
  const int col = lane & 15;
  const int quad = lane >> 4;

  f32x4 acc[4][4];
#pragma unroll
  for (int i = 0; i < 4; i++)
#pragma unroll
    for (int j = 0; j < 4; j++) acc[i][j] = f32x4{0.f, 0.f, 0.f, 0.f};

  const int ci0 = t, ci1 = 256 + t;
  const int r0 = ci0 >> 2, c0 = ci0 & 3;
  const int r1 = ci1 >> 2, c1 = ci1 & 3;

  s16x8 pa0 = pack8(X + (size_t)(m0 + r0) * DD + c0 * 8);
  s16x8 pa1 = pack8(X + (size_t)(m0 + r1) * DD + c1 * 8);
  s16x8 pb0 = pack8(Wsel + (size_t)(n0l + r0) * DD + c0 * 8);
  s16x8 pb1 = pack8(Wsel + (size_t)(n0l + r1) * DD + c1 * 8);

  for (int kk = 0; kk < DD; kk += 32) {
    __syncthreads();
    *(s16x8*)&Al[r0 * LROW + c0 * 8] = pa0;
    *(s16x8*)&Al[r1 * LROW + c1 * 8] = pa1;
    *(s16x8*)&Bl[r0 * LROW + c0 * 8] = pb0;
    *(s16x8*)&Bl[r1 * LROW + c1 * 8] = pb1;
    __syncthreads();
    const int kn = kk + 32;
    if (kn < DD) {
      pa0 = pack8(X + (size_t)(m0 + r0) * DD + kn + c0 * 8);
      pa1 = pack8(X + (size_t)(m0 + r1) * DD + kn + c1 * 8);
      pb0 = pack8(Wsel + (size_t)(n0l + r0) * DD + kn + c0 * 8);
      pb1 = pack8(Wsel + (size_t)(n0l + r1) * DD + kn + c1 * 8);
    }
    s16x8 af[4], bfr[4];
#pragma unroll
    for (int mi = 0; mi < 4; mi++)
      af[mi] = *(const s16x8*)&Al[(wr * 64 + mi * 16 + col) * LROW + quad * 8];
#pragma unroll
    for (int ni = 0; ni < 4; ni++)
      bfr[ni] = *(const s16x8*)&Bl[(wc * 64 + ni * 16 + col) * LROW + quad * 8];
#pragma unroll
    for (int mi = 0; mi < 4; mi++)
#pragma unroll
      for (int ni = 0; ni < 4; ni++)
        acc[mi][ni] = __builtin_amdgcn_mfma_f32_16x16x32_bf16(af[mi], bfr[ni], acc[mi][ni], 0, 0, 0);
  }

#pragma unroll
  for (int mi = 0; mi < 4; mi++) {
    const int gm = m0 + wr * 64 + mi * 16 + quad * 4;
#pragma unroll
    for (int ni = 0; ni < 4; ni++) {
      const int gnl = n0l + wc * 64 + ni * 16 + col;
      const float bb = bsel[gnl];
      f32x4 v = acc[mi][ni];
      if (region == 0) {
#pragma unroll
        for (int rg = 0; rg < 4; rg++)
          Qb[(size_t)(gm + rg) * DD + gnl] = f2bf((v[rg] + bb) * 0.015625f);  // exact /64
      } else if (region == 1) {
#pragma unroll
        for (int rg = 0; rg < 4; rg++)
          Kb[(size_t)(gm + rg) * DD + gnl] = f2bf(v[rg] + bb);
      } else {
        const int b = gm >> 12;
        const int s = gm & (SS - 1);
        ushort4 o = { f2bf(v[0] + bb), f2bf(v[1] + bb), f2bf(v[2] + bb), f2bf(v[3] + bb) };
        *(ushort4*)&Vt[((size_t)(b << 8) + gnl) * SS + s] = o;
      }
    }
  }
}

// ---------------- kernel 2: flash attention ----------------
// 256-THREAD BLOCKS (R12 finding: 512-thread workgroups never exceed 8
// waves/CU regardless of LDS 42-75 KB / VGPR 108 — apparent 1-WG/CU policy
// for large workgroups; the only verified multi-WG data points are 256-thread
// blocks at ~3 WG/CU). Grid (64 qt, 4 b, nz): each block = 4 waves x 16 q-rows,
// processes KV range [z*SS/nz, (z+1)*SS/nz), writes an UNNORMALIZED partial
// O + (m,l); merge_kernel combines the nz partials exactly.
// nz chosen at launch from ws_size: 4 (76 MB ws) if it fits, else 2 (42 MB,
// R12-proven) — guards against the suspected R9/R10 ws-overflow container kill.
// K/V time-share one LDS region (R8). Strides: KROW 264 (132 dw, odd quad),
// VROW/PROW 40 (20 dw, odd quad) — 16B-aligned (R6 rule) AND conflict-free
// for 16-lane b128 (R12's 32-u strides were 8-way aliased).
#define NKT 32
#define KROW 264   // 528B
#define VROW 40    //  80B
#define PROW 40

#define KVREG_U 10240            // max(K tile 32*264=8448, V tile 256*40=10240)
#define PL_U (16 * PROW)         // 640 per wave
#define POFF KVREG_U             // 10240
#define SM_U (POFF + 4 * PL_U)   // 12800 ushorts = 25600 B

__global__ __launch_bounds__(256, 4) void attn_kernel(const ushort* __restrict__ Qb,
                                                      const ushort* __restrict__ Kb,
                                                      const ushort* __restrict__ Vt,
                                                      const int* __restrict__ mask,
                                                      float* __restrict__ out,
                                                      float* __restrict__ Opart,
                                                      float* __restrict__ Ml,
                                                      const int NT2) {
  __shared__ __align__(16) ushort sm[SM_U];

  const int qt = blockIdx.x;  // 0..63
  const int b = blockIdx.y;   // 0..3
  const int z = blockIdx.z;   // 0..nz-1 (KV slice)
  const int t = threadIdx.x;  // 0..255
  const int lane = t & 63;
  const int w = t >> 6;       // wave: 0..3
  const int col = lane & 15;
  const int quad = lane >> 4;

  ushort* Kl = sm;            // K and V time-share this region
  ushort* Vl = sm;
  ushort* Pw = sm + POFF + w * PL_U;

  const int qrow = qt * 64 + w * 16;  // wave's first q row (within batch)

  // Q fragments (A-operand), pre-scaled by 1/64
  s16x8 qf[8];
  {
    const ushort* qp = Qb + ((size_t)b * SS + qrow + col) * DD + quad * 8;
#pragma unroll
    for (int dc = 0; dc < 8; dc++) qf[dc] = *(const s16x8*)(qp + dc * 32);
  }

  int kr[4], kc[4], vd[4], vc[4];
#pragma unroll
  for (int i = 0; i < 4; i++) {
    const int ci = i * 256 + t;
    kr[i] = ci >> 5; kc[i] = ci & 31;  // K tile: 32 rows x 32 chunks(8)
    vd[i] = ci >> 2; vc[i] = ci & 3;   // Vt tile: 256 d-rows x 4 chunks(8)
  }

  const ushort* Kg = Kb + (size_t)b * SS * DD;
  const ushort* Vg = Vt + (size_t)b * DD * SS;
  const int* Mg = mask + ((size_t)b * SS + qrow + quad * 4) * SS;

  f32x4 Oc[16];
#pragma unroll
  for (int i = 0; i < 16; i++) Oc[i] = f32x4{0.f, 0.f, 0.f, 0.f};
  float m_i[4] = {-INFINITY, -INFINITY, -INFINITY, -INFINITY};
  float l_i[4] = {0.f, 0.f, 0.f, 0.f};

  const int kb0 = z * NT2 * NKT;  // this block's first kv position

  // prefetch tile 0 into registers
  s16x8 pk[4], pv[4];
  int pm[2][4];
#pragma unroll
  for (int i = 0; i < 4; i++) {
    pk[i] = *(const s16x8*)(Kg + (size_t)(kb0 + kr[i]) * DD + kc[i] * 8);
    pv[i] = *(const s16x8*)(Vg + (size_t)vd[i] * SS + kb0 + vc[i] * 8);
  }
#pragma unroll
  for (int jt = 0; jt < 2; jt++)
#pragma unroll
    for (int rg = 0; rg < 4; rg++) pm[jt][rg] = Mg[rg * SS + kb0 + jt * 16 + col];

  for (int tt = 0; tt < NT2; tt++) {
    __syncthreads();   // B1: prior PV reads of shared region done
#pragma unroll
    for (int i = 0; i < 4; i++)
      *(s16x8*)&Kl[kr[i] * KROW + kc[i] * 8] = pk[i];
    __syncthreads();   // B2: K tile visible
    int mcur[2][4];
#pragma unroll
    for (int jt = 0; jt < 2; jt++)
#pragma unroll
      for (int rg = 0; rg < 4; rg++) mcur[jt][rg] = pm[jt][rg];
    const int k0n = kb0 + (tt + 1) * NKT;
    if (tt + 1 < NT2) {
#pragma unroll
      for (int i = 0; i < 4; i++)
        pk[i] = *(const s16x8*)(Kg + ((size_t)k0n + kr[i]) * DD + kc[i] * 8);
#pragma unroll
      for (int jt = 0; jt < 2; jt++)
#pragma unroll
        for (int rg = 0; rg < 4; rg++) pm[jt][rg] = Mg[rg * SS + k0n + jt * 16 + col];
    }

    // S = Q K^T (pre-scaled): 2 col-tiles x 8 d-chunks
    f32x4 st[2];
    __builtin_amdgcn_s_setprio(1);
#pragma unroll
    for (int jt = 0; jt < 2; jt++) {
      f32x4 s = f32x4{0.f, 0.f, 0.f, 0.f};
#pragma unroll
      for (int dc = 0; dc < 8; dc++) {
        s16x8 kb = *(const s16x8*)&Kl[(jt * 16 + col) * KROW + dc * 32 + quad * 8];
        s = __builtin_amdgcn_mfma_f32_16x16x32_bf16(qf[dc], kb, s, 0, 0, 0);
      }
      st[jt] = s;
    }
    __builtin_amdgcn_s_setprio(0);
    // mask (nonzero -> -1e9, post-scale, matching reference)
#pragma unroll
    for (int jt = 0; jt < 2; jt++)
#pragma unroll
      for (int rg = 0; rg < 4; rg++)
        if (mcur[jt][rg]) st[jt][rg] = -1e9f;

    // online softmax: per q-row (row = quad*4+rg), reduce over 16 col lanes
    float al[4];
#pragma unroll
    for (int rg = 0; rg < 4; rg++) {
      float v = fmaxf(st[0][rg], st[1][rg]);
      v = fmaxf(v, __shfl_xor(v, 1));
      v = fmaxf(v, __shfl_xor(v, 2));
      v = fmaxf(v, __shfl_xor(v, 4));
      v = fmaxf(v, __shfl_xor(v, 8));
      const float mn = fmaxf(m_i[rg], v);
      al[rg] = __expf(m_i[rg] - mn);
      m_i[rg] = mn;
    }
#pragma unroll
    for (int rg = 0; rg < 4; rg++) {
      const float p0 = __expf(st[0][rg] - m_i[rg]);
      const float p1 = __expf(st[1][rg] - m_i[rg]);
      st[0][rg] = p0; st[1][rg] = p1;
      float s2 = p0 + p1;
      s2 += __shfl_xor(s2, 1);
      s2 += __shfl_xor(s2, 2);
      s2 += __shfl_xor(s2, 4);
      s2 += __shfl_xor(s2, 8);
      l_i[rg] = l_i[rg] * al[rg] + s2;
    }

    // P: C-layout -> LDS -> A-layout (own per-wave region)
#pragma unroll
    for (int jt = 0; jt < 2; jt++)
#pragma unroll
      for (int rg = 0; rg < 4; rg++)
        Pw[(quad * 4 + rg) * PROW + jt * 16 + col] = f2bf(st[jt][rg]);
    s16x8 pa = *(const s16x8*)&Pw[col * PROW + quad * 8];

    // O rescale — EXACT skip: al==1.0 is identity
    {
      const bool need = (al[0] < 1.f) | (al[1] < 1.f) | (al[2] < 1.f) | (al[3] < 1.f);
      if (__any(need)) {
#pragma unroll
        for (int dt = 0; dt < 16; dt++)
#pragma unroll
          for (int rg = 0; rg < 4; rg++) Oc[dt][rg] *= al[rg];
      }
    }

    __syncthreads();   // B3: all QK^T reads done; shared region free for V
#pragma unroll
    for (int i = 0; i < 4; i++)
      *(s16x8*)&Vl[vd[i] * VROW + vc[i] * 8] = pv[i];
    if (tt + 1 < NT2) {
#pragma unroll
      for (int i = 0; i < 4; i++)
        pv[i] = *(const s16x8*)(Vg + (size_t)vd[i] * SS + k0n + vc[i] * 8);
    }
    __syncthreads();   // B4: V tile visible

    // O += P * V
    __builtin_amdgcn_s_setprio(1);
#pragma unroll
    for (int dt = 0; dt < 16; dt++) {
      s16x8 vb = *(const s16x8*)&Vl[(dt * 16 + col) * VROW + quad * 8];
      Oc[dt] = __builtin_amdgcn_mfma_f32_16x16x32_bf16(pa, vb, Oc[dt], 0, 0, 0);
    }
    __builtin_amdgcn_s_setprio(0);
  }

  // ---- write this z-slice's unnormalized partial (no in-block merge) ----
  float* op = (z == 0 ? out : Opart + (size_t)(z - 1) * BB * SS * DD) +
              ((size_t)b * SS + qrow + quad * 4) * DD;
#pragma unroll
  for (int dt = 0; dt < 16; dt++) {
#pragma unroll
    for (int rg = 0; rg < 4; rg++)
      op[rg * DD + dt * 16 + col] = Oc[dt][rg];
  }
  if (col == 0) {
    float2* pml = (float2*)Ml + (size_t)z * BB * SS + (size_t)b * SS + qrow + quad * 4;
#pragma unroll
    for (int rg = 0; rg < 4; rg++) pml[rg] = make_float2(m_i[rg], l_i[rg]);
  }
}

// ---------------- kernel 3: cross-z softmax merge (nz partials) ----------------
__global__ __launch_bounds__(256) void merge_kernel(const float* __restrict__ Ml,
                                                    const float* __restrict__ Opart,
                                                    float* __restrict__ out,
                                                    const int nz) {
  const int row = blockIdx.x * 4 + (threadIdx.x >> 6);  // 0..BB*SS-1
  const int lane = threadIdx.x & 63;
  float mz[4], lz[4];
  float mm = -INFINITY;
  for (int zz = 0; zz < nz; zz++) {
    const float2 ml = ((const float2*)Ml)[(size_t)zz * BB * SS + row];
    mz[zz] = ml.x; lz[zz] = ml.y;
    mm = fmaxf(mm, ml.x);
  }
  float a[4], L = 0.f;
  for (int zz = 0; zz < nz; zz++) {
    a[zz] = __expf(mz[zz] - mm);
    L += lz[zz] * a[zz];
  }
  const float inv = 1.0f / L;
  f32x4* po = (f32x4*)out + (size_t)row * 64 + lane;
  f32x4 acc = *po;
#pragma unroll 4
  for (int j = 0; j < 4; j++) acc[j] *= a[0];
  for (int zz = 1; zz < nz; zz++) {
    const f32x4 o = ((const f32x4*)(Opart + (size_t)(zz - 1) * BB * SS * DD))[(size_t)row * 64 + lane];
#pragma unroll 4
    for (int j = 0; j < 4; j++) acc[j] += o[j] * a[zz];
  }
#pragma unroll 4
  for (int j = 0; j < 4; j++) acc[j] *= inv;
  *po = acc;
}

extern "C" void kernel_launch(void* const* d_in, const int* in_sizes, int n_in,
                              void* d_out, int out_size, void* d_ws, size_t ws_size,
                              hipStream_t stream) {
  const float* X  = (const float*)d_in[0];
  const int* mask = (const int*)d_in[1];
  const float* Wq = (const float*)d_in[2];
  const float* bq = (const float*)d_in[3];
  const float* Wk = (const float*)d_in[4];
  const float* bk = (const float*)d_in[5];
  const float* Wv = (const float*)d_in[6];
  const float* bv = (const float*)d_in[7];
  float* out = (float*)d_out;

  ushort* base = (ushort*)d_ws;
  ushort* Qb = base;                                   // 8.4 MB
  ushort* Kb = Qb + (size_t)BB * SS * DD;              // 8.4 MB
  ushort* Vt = Kb + (size_t)BB * SS * DD;              // 8.4 MB
  float* Ml = (float*)(Vt + (size_t)BB * SS * DD);     // 4 z-sets x BB*SS float2 = 0.5 MB
  float* Opart = Ml + (size_t)8 * BB * SS;             // (nz-1) x 16.8 MB

  // choose KV split from available workspace (suspected R9/R10 container kill
  // was ws overflow at 59 MB; 42.5 MB is R12-proven)
  const size_t fixed = (size_t)3 * BB * SS * DD * 2 + (size_t)8 * BB * SS * 4;
  const size_t need4 = fixed + (size_t)3 * BB * SS * DD * 4;  // ~76.0 MB
  const int nz = (ws_size >= need4) ? 4 : 2;
  const int NT2 = (SS / NKT) / nz;

  proj_gemm<<<dim3(128, 6), 256, 0, stream>>>(X, Wq, Wk, Wv, bq, bk, bv, Qb, Kb, Vt);
  attn_kernel<<<dim3(64, 4, nz), 256, 0, stream>>>(Qb, Kb, Vt, mask, out, Opart, Ml, NT2);
  merge_kernel<<<(BB * SS) / 4, 256, 0, stream>>>(Ml, Opart, out, nz);
}

// Round 14
// 678.896 us; speedup vs baseline: 1.7031x; 1.7031x over previous
//
#include <hip/hip_runtime.h>
#include <hip/hip_bf16.h>
#include <stdint.h>

#define BB 4
#define SS 4096
#define DD 256

typedef __attribute__((ext_vector_type(4))) float f32x4;
typedef __attribute__((ext_vector_type(8))) short s16x8;

__device__ __forceinline__ ushort f2bf(float f) {
  __hip_bfloat16 h = __float2bfloat16(f);
  return __builtin_bit_cast(ushort, h);
}

// pack 8 consecutive f32 -> 8 bf16 (RNE)
__device__ __forceinline__ s16x8 pack8(const float* __restrict__ p) {
  const float4 a = *(const float4*)p;
  const float4 b = *(const float4*)(p + 4);
  s16x8 r;
  r[0] = (short)f2bf(a.x); r[1] = (short)f2bf(a.y);
  r[2] = (short)f2bf(a.z); r[3] = (short)f2bf(a.w);
  r[4] = (short)f2bf(b.x); r[5] = (short)f2bf(b.y);
  r[6] = (short)f2bf(b.z); r[7] = (short)f2bf(b.w);
  return r;
}

// ---------------- kernel 1: fused convert + QKV projection GEMM ----------------
#define LROW 40  // 80B row stride: multiple of 16B (b128-safe), odd dw-quad (conflict-free)

__global__ __launch_bounds__(256) void proj_gemm(const float* __restrict__ X,
                                                 const float* __restrict__ Wq,
                                                 const float* __restrict__ Wk,
                                                 const float* __restrict__ Wv,
                                                 const float* __restrict__ bq,
                                                 const float* __restrict__ bk,
                                                 const float* __restrict__ bv,
                                                 ushort* __restrict__ Qb,
                                                 ushort* __restrict__ Kb,
                                                 ushort* __restrict__ Vt) {
  __shared__ ushort Al[128 * LROW];
  __shared__ ushort Bl[128 * LROW];
  const int m0 = blockIdx.x * 128;
  const int n0 = blockIdx.y * 128;
  const int region = n0 >> 8;          // 0=Q, 1=K, 2=V (blocks never straddle)
  const int n0l = n0 & 255;
  const float* Wsel = (region == 0) ? Wq : (region == 1) ? Wk : Wv;
  const float* bsel = (region == 0) ? bq : (region == 1) ? bk : bv;
  const int t = threadIdx.x;
  const int lane = t & 63;
  const int w = t >> 6;
  const int wr = w & 1, wc = w >> 1;
  const int col = lane & 15;
  const int quad = lane >> 4;

  f32x4 acc[4][4];
#pragma unroll
  for (int i = 0; i < 4; i++)
#pragma unroll
    for (int j = 0; j < 4; j++) acc[i][j] = f32x4{0.f, 0.f, 0.f, 0.f};

  const int ci0 = t, ci1 = 256 + t;
  const int r0 = ci0 >> 2, c0 = ci0 & 3;
  const int r1 = ci1 >> 2, c1 = ci1 & 3;

  s16x8 pa0 = pack8(X + (size_t)(m0 + r0) * DD + c0 * 8);
  s16x8 pa1 = pack8(X + (size_t)(m0 + r1) * DD + c1 * 8);
  s16x8 pb0 = pack8(Wsel + (size_t)(n0l + r0) * DD + c0 * 8);
  s16x8 pb1 = pack8(Wsel + (size_t)(n0l + r1) * DD + c1 * 8);

  for (int kk = 0; kk < DD; kk += 32) {
    __syncthreads();
    *(s16x8*)&Al[r0 * LROW + c0 * 8] = pa0;
    *(s16x8*)&Al[r1 * LROW + c1 * 8] = pa1;
    *(s16x8*)&Bl[r0 * LROW + c0 * 8] = pb0;
    *(s16x8*)&Bl[r1 * LROW + c1 * 8] = pb1;
    __syncthreads();
    const int kn = kk + 32;
    if (kn < DD) {
      pa0 = pack8(X + (size_t)(m0 + r0) * DD + kn + c0 * 8);
      pa1 = pack8(X + (size_t)(m0 + r1) * DD + kn + c1 * 8);
      pb0 = pack8(Wsel + (size_t)(n0l + r0) * DD + kn + c0 * 8);
      pb1 = pack8(Wsel + (size_t)(n0l + r1) * DD + kn + c1 * 8);
    }
    s16x8 af[4], bfr[4];
#pragma unroll
    for (int mi = 0; mi < 4; mi++)
      af[mi] = *(const s16x8*)&Al[(wr * 64 + mi * 16 + col) * LROW + quad * 8];
#pragma unroll
    for (int ni = 0; ni < 4; ni++)
      bfr[ni] = *(const s16x8*)&Bl[(wc * 64 + ni * 16 + col) * LROW + quad * 8];
#pragma unroll
    for (int mi = 0; mi < 4; mi++)
#pragma unroll
      for (int ni = 0; ni < 4; ni++)
        acc[mi][ni] = __builtin_amdgcn_mfma_f32_16x16x32_bf16(af[mi], bfr[ni], acc[mi][ni], 0, 0, 0);
  }

#pragma unroll
  for (int mi = 0; mi < 4; mi++) {
    const int gm = m0 + wr * 64 + mi * 16 + quad * 4;
#pragma unroll
    for (int ni = 0; ni < 4; ni++) {
      const int gnl = n0l + wc * 64 + ni * 16 + col;
      const float bb = bsel[gnl];
      f32x4 v = acc[mi][ni];
      if (region == 0) {
#pragma unroll
        for (int rg = 0; rg < 4; rg++)
          Qb[(size_t)(gm + rg) * DD + gnl] = f2bf((v[rg] + bb) * 0.015625f);  // exact /64
      } else if (region == 1) {
#pragma unroll
        for (int rg = 0; rg < 4; rg++)
          Kb[(size_t)(gm + rg) * DD + gnl] = f2bf(v[rg] + bb);
      } else {
        const int b = gm >> 12;
        const int s = gm & (SS - 1);
        ushort4 o = { f2bf(v[0] + bb), f2bf(v[1] + bb), f2bf(v[2] + bb), f2bf(v[3] + bb) };
        *(ushort4*)&Vt[((size_t)(b << 8) + gnl) * SS + s] = o;
      }
    }
  }
}

// ---------------- kernel 2: flash attention ----------------
// 256-thread blocks, grid (64 qt, 4 b, nz). R13 PROVED the co-residency:
// occupancy hit 47% (4 blocks/CU) — 256-thread WGs co-schedule where 512/1024
// never exceeded 1 WG/CU. R13's regression was the REGISTER HINT:
// __launch_bounds__(256, 4) retriggered hipcc's 64-VGPR/8-wave heuristic and
// spilled the accumulators (3.2 GB scratch traffic), exactly like R3-R5.
// REGISTER RULE (R0/R2/R12 vs R3/R4/R5/R13): plain __launch_bounds__(N) gives
// a sane no-spill allocation (152@256t, 108@512t); ANY occupancy hint
// ((N,waves) or amdgpu_waves_per_eu) collapses to 64 VGPR + spill. Never hint.
// Each block = 4 waves x 16 q-rows, KV slice [z*SS/nz,(z+1)*SS/nz), writes an
// UNNORMALIZED partial O + (m,l); merge_kernel combines nz partials exactly.
// K/V time-share one LDS region (R8). Strides KROW 264 / VROW,PROW 40:
// 16B-aligned (R6 rule) and odd dw-quad (conflict-free b128).
#define NKT 32
#define KROW 264   // 528B
#define VROW 40    //  80B
#define PROW 40

#define KVREG_U 10240            // max(K tile 32*264=8448, V tile 256*40=10240)
#define PL_U (16 * PROW)         // 640 per wave
#define POFF KVREG_U             // 10240
#define SM_U (POFF + 4 * PL_U)   // 12800 ushorts = 25600 B

__global__ __launch_bounds__(256) void attn_kernel(const ushort* __restrict__ Qb,
                                                   const ushort* __restrict__ Kb,
                                                   const ushort* __restrict__ Vt,
                                                   const int* __restrict__ mask,
                                                   float* __restrict__ out,
                                                   float* __restrict__ Opart,
                                                   float* __restrict__ Ml,
                                                   const int NT2) {
  __shared__ __align__(16) ushort sm[SM_U];

  const int qt = blockIdx.x;  // 0..63
  const int b = blockIdx.y;   // 0..3
  const int z = blockIdx.z;   // 0..nz-1 (KV slice)
  const int t = threadIdx.x;  // 0..255
  const int lane = t & 63;
  const int w = t >> 6;       // wave: 0..3
  const int col = lane & 15;
  const int quad = lane >> 4;

  ushort* Kl = sm;            // K and V time-share this region
  ushort* Vl = sm;
  ushort* Pw = sm + POFF + w * PL_U;

  const int qrow = qt * 64 + w * 16;  // wave's first q row (within batch)

  // Q fragments (A-operand), pre-scaled by 1/64
  s16x8 qf[8];
  {
    const ushort* qp = Qb + ((size_t)b * SS + qrow + col) * DD + quad * 8;
#pragma unroll
    for (int dc = 0; dc < 8; dc++) qf[dc] = *(const s16x8*)(qp + dc * 32);
  }

  int kr[4], kc[4], vd[4], vc[4];
#pragma unroll
  for (int i = 0; i < 4; i++) {
    const int ci = i * 256 + t;
    kr[i] = ci >> 5; kc[i] = ci & 31;  // K tile: 32 rows x 32 chunks(8)
    vd[i] = ci >> 2; vc[i] = ci & 3;   // Vt tile: 256 d-rows x 4 chunks(8)
  }

  const ushort* Kg = Kb + (size_t)b * SS * DD;
  const ushort* Vg = Vt + (size_t)b * DD * SS;
  const int* Mg = mask + ((size_t)b * SS + qrow + quad * 4) * SS;

  f32x4 Oc[16];
#pragma unroll
  for (int i = 0; i < 16; i++) Oc[i] = f32x4{0.f, 0.f, 0.f, 0.f};
  float m_i[4] = {-INFINITY, -INFINITY, -INFINITY, -INFINITY};
  float l_i[4] = {0.f, 0.f, 0.f, 0.f};

  const int kb0 = z * NT2 * NKT;  // this block's first kv position

  // prefetch tile 0 into registers
  s16x8 pk[4], pv[4];
  int pm[2][4];
#pragma unroll
  for (int i = 0; i < 4; i++) {
    pk[i] = *(const s16x8*)(Kg + (size_t)(kb0 + kr[i]) * DD + kc[i] * 8);
    pv[i] = *(const s16x8*)(Vg + (size_t)vd[i] * SS + kb0 + vc[i] * 8);
  }
#pragma unroll
  for (int jt = 0; jt < 2; jt++)
#pragma unroll
    for (int rg = 0; rg < 4; rg++) pm[jt][rg] = Mg[rg * SS + kb0 + jt * 16 + col];

  for (int tt = 0; tt < NT2; tt++) {
    __syncthreads();   // B1: prior PV reads of shared region done
#pragma unroll
    for (int i = 0; i < 4; i++)
      *(s16x8*)&Kl[kr[i] * KROW + kc[i] * 8] = pk[i];
    __syncthreads();   // B2: K tile visible
    int mcur[2][4];
#pragma unroll
    for (int jt = 0; jt < 2; jt++)
#pragma unroll
      for (int rg = 0; rg < 4; rg++) mcur[jt][rg] = pm[jt][rg];
    const int k0n = kb0 + (tt + 1) * NKT;
    if (tt + 1 < NT2) {
#pragma unroll
      for (int i = 0; i < 4; i++)
        pk[i] = *(const s16x8*)(Kg + ((size_t)k0n + kr[i]) * DD + kc[i] * 8);
#pragma unroll
      for (int jt = 0; jt < 2; jt++)
#pragma unroll
        for (int rg = 0; rg < 4; rg++) pm[jt][rg] = Mg[rg * SS + k0n + jt * 16 + col];
    }

    // S = Q K^T (pre-scaled): 2 col-tiles x 8 d-chunks
    f32x4 st[2];
    __builtin_amdgcn_s_setprio(1);
#pragma unroll
    for (int jt = 0; jt < 2; jt++) {
      f32x4 s = f32x4{0.f, 0.f, 0.f, 0.f};
#pragma unroll
      for (int dc = 0; dc < 8; dc++) {
        s16x8 kb = *(const s16x8*)&Kl[(jt * 16 + col) * KROW + dc * 32 + quad * 8];
        s = __builtin_amdgcn_mfma_f32_16x16x32_bf16(qf[dc], kb, s, 0, 0, 0);
      }
      st[jt] = s;
    }
    __builtin_amdgcn_s_setprio(0);
    // mask (nonzero -> -1e9, post-scale, matching reference)
#pragma unroll
    for (int jt = 0; jt < 2; jt++)
#pragma unroll
      for (int rg = 0; rg < 4; rg++)
        if (mcur[jt][rg]) st[jt][rg] = -1e9f;

    // online softmax: per q-row (row = quad*4+rg), reduce over 16 col lanes
    float al[4];
#pragma unroll
    for (int rg = 0; rg < 4; rg++) {
      float v = fmaxf(st[0][rg], st[1][rg]);
      v = fmaxf(v, __shfl_xor(v, 1));
      v = fmaxf(v, __shfl_xor(v, 2));
      v = fmaxf(v, __shfl_xor(v, 4));
      v = fmaxf(v, __shfl_xor(v, 8));
      const float mn = fmaxf(m_i[rg], v);
      al[rg] = __expf(m_i[rg] - mn);
      m_i[rg] = mn;
    }
#pragma unroll
    for (int rg = 0; rg < 4; rg++) {
      const float p0 = __expf(st[0][rg] - m_i[rg]);
      const float p1 = __expf(st[1][rg] - m_i[rg]);
      st[0][rg] = p0; st[1][rg] = p1;
      float s2 = p0 + p1;
      s2 += __shfl_xor(s2, 1);
      s2 += __shfl_xor(s2, 2);
      s2 += __shfl_xor(s2, 4);
      s2 += __shfl_xor(s2, 8);
      l_i[rg] = l_i[rg] * al[rg] + s2;
    }

    // P: C-layout -> LDS -> A-layout (own per-wave region)
#pragma unroll
    for (int jt = 0; jt < 2; jt++)
#pragma unroll
      for (int rg = 0; rg < 4; rg++)
        Pw[(quad * 4 + rg) * PROW + jt * 16 + col] = f2bf(st[jt][rg]);
    s16x8 pa = *(const s16x8*)&Pw[col * PROW + quad * 8];

    // O rescale — EXACT skip: al==1.0 is identity
    {
      const bool need = (al[0] < 1.f) | (al[1] < 1.f) | (al[2] < 1.f) | (al[3] < 1.f);
      if (__any(need)) {
#pragma unroll
        for (int dt = 0; dt < 16; dt++)
#pragma unroll
          for (int rg = 0; rg < 4; rg++) Oc[dt][rg] *= al[rg];
      }
    }

    __syncthreads();   // B3: all QK^T reads done; shared region free for V
#pragma unroll
    for (int i = 0; i < 4; i++)
      *(s16x8*)&Vl[vd[i] * VROW + vc[i] * 8] = pv[i];
    if (tt + 1 < NT2) {
#pragma unroll
      for (int i = 0; i < 4; i++)
        pv[i] = *(const s16x8*)(Vg + (size_t)vd[i] * SS + k0n + vc[i] * 8);
    }
    __syncthreads();   // B4: V tile visible

    // O += P * V
    __builtin_amdgcn_s_setprio(1);
#pragma unroll
    for (int dt = 0; dt < 16; dt++) {
      s16x8 vb = *(const s16x8*)&Vl[(dt * 16 + col) * VROW + quad * 8];
      Oc[dt] = __builtin_amdgcn_mfma_f32_16x16x32_bf16(pa, vb, Oc[dt], 0, 0, 0);
    }
    __builtin_amdgcn_s_setprio(0);
  }

  // ---- write this z-slice's unnormalized partial (no in-block merge) ----
  float* op = (z == 0 ? out : Opart + (size_t)(z - 1) * BB * SS * DD) +
              ((size_t)b * SS + qrow + quad * 4) * DD;
#pragma unroll
  for (int dt = 0; dt < 16; dt++) {
#pragma unroll
    for (int rg = 0; rg < 4; rg++)
      op[rg * DD + dt * 16 + col] = Oc[dt][rg];
  }
  if (col == 0) {
    float2* pml = (float2*)Ml + (size_t)z * BB * SS + (size_t)b * SS + qrow + quad * 4;
#pragma unroll
    for (int rg = 0; rg < 4; rg++) pml[rg] = make_float2(m_i[rg], l_i[rg]);
  }
}

// ---------------- kernel 3: cross-z softmax merge (nz partials) ----------------
__global__ __launch_bounds__(256) void merge_kernel(const float* __restrict__ Ml,
                                                    const float* __restrict__ Opart,
                                                    float* __restrict__ out,
                                                    const int nz) {
  const int row = blockIdx.x * 4 + (threadIdx.x >> 6);  // 0..BB*SS-1
  const int lane = threadIdx.x & 63;
  float mz[4], lz[4];
  float mm = -INFINITY;
  for (int zz = 0; zz < nz; zz++) {
    const float2 ml = ((const float2*)Ml)[(size_t)zz * BB * SS + row];
    mz[zz] = ml.x; lz[zz] = ml.y;
    mm = fmaxf(mm, ml.x);
  }
  float a[4], L = 0.f;
  for (int zz = 0; zz < nz; zz++) {
    a[zz] = __expf(mz[zz] - mm);
    L += lz[zz] * a[zz];
  }
  const float inv = 1.0f / L;
  f32x4* po = (f32x4*)out + (size_t)row * 64 + lane;
  f32x4 acc = *po;
#pragma unroll 4
  for (int j = 0; j < 4; j++) acc[j] *= a[0];
  for (int zz = 1; zz < nz; zz++) {
    const f32x4 o = ((const f32x4*)(Opart + (size_t)(zz - 1) * BB * SS * DD))[(size_t)row * 64 + lane];
#pragma unroll 4
    for (int j = 0; j < 4; j++) acc[j] += o[j] * a[zz];
  }
#pragma unroll 4
  for (int j = 0; j < 4; j++) acc[j] *= inv;
  *po = acc;
}

extern "C" void kernel_launch(void* const* d_in, const int* in_sizes, int n_in,
                              void* d_out, int out_size, void* d_ws, size_t ws_size,
                              hipStream_t stream) {
  const float* X  = (const float*)d_in[0];
  const int* mask = (const int*)d_in[1];
  const float* Wq = (const float*)d_in[2];
  const float* bq = (const float*)d_in[3];
  const float* Wk = (const float*)d_in[4];
  const float* bk = (const float*)d_in[5];
  const float* Wv = (const float*)d_in[6];
  const float* bv = (const float*)d_in[7];
  float* out = (float*)d_out;

  ushort* base = (ushort*)d_ws;
  ushort* Qb = base;                                   // 8.4 MB
  ushort* Kb = Qb + (size_t)BB * SS * DD;              // 8.4 MB
  ushort* Vt = Kb + (size_t)BB * SS * DD;              // 8.4 MB
  float* Ml = (float*)(Vt + (size_t)BB * SS * DD);     // 4 z-sets x BB*SS float2 = 0.5 MB
  float* Opart = Ml + (size_t)8 * BB * SS;             // (nz-1) x 16.8 MB

  // choose KV split from available workspace (R13 ran nz=4 / 76 MB fine)
  const size_t fixed = (size_t)3 * BB * SS * DD * 2 + (size_t)8 * BB * SS * 4;
  const size_t need4 = fixed + (size_t)3 * BB * SS * DD * 4;  // ~76.0 MB
  const int nz = (ws_size >= need4) ? 4 : 2;
  const int NT2 = (SS / NKT) / nz;

  proj_gemm<<<dim3(128, 6), 256, 0, stream>>>(X, Wq, Wk, Wv, bq, bk, bv, Qb, Kb, Vt);
  attn_kernel<<<dim3(64, 4, nz), 256, 0, stream>>>(Qb, Kb, Vt, mask, out, Opart, Ml, NT2);
  merge_kernel<<<(BB * SS) / 4, 256, 0, stream>>>(Ml, Opart, out, nz);
}